// Round 2
// baseline (110.370 us; speedup 1.0000x reference)
//
#include <hip/hip_runtime.h>

// DotPred: score[t,e] = sum_d (x[src[t,e],d] - x[dst[t,e],d]) / sqrt(D)
//        = (rowsum(x)[src] - rowsum(x)[dst]) * (1/sqrt(D))
// Two-phase: (1) per-node rowsum into d_ws, (2) per-edge gather/subtract.
// NOTE: indices arrive as int32 (JAX x64 disabled; harness: integer -> const int*).

#define IN_DIM 128
#define INV_SQRT_D 0.08838834764831843f  // 1/sqrt(128)

// One 64-lane wave per node row. Each lane loads float2 (64*8B = 512B = full row).
__global__ void rowsum_kernel(const float* __restrict__ x,
                              float* __restrict__ S, int n_nodes) {
    const int gtid = blockIdx.x * blockDim.x + threadIdx.x;
    const int row  = gtid >> 6;          // wave index = node row
    const int lane = threadIdx.x & 63;
    if (row >= n_nodes) return;

    const float2 v = ((const float2*)(x + (size_t)row * IN_DIM))[lane];
    float s = v.x + v.y;

    // 64-lane butterfly reduction
    #pragma unroll
    for (int off = 32; off > 0; off >>= 1)
        s += __shfl_xor(s, off, 64);

    if (lane == 0) S[row] = s;
}

// One thread per edge slot (flat over [T, E]).
__global__ void edge_kernel(const int* __restrict__ src,
                            const int* __restrict__ dst,
                            const float* __restrict__ S,
                            float* __restrict__ out, int n) {
    const int i = blockIdx.x * blockDim.x + threadIdx.x;
    if (i >= n) return;
    const int s = src[i];
    const int d = dst[i];
    out[i] = (S[s] - S[d]) * INV_SQRT_D;
}

extern "C" void kernel_launch(void* const* d_in, const int* in_sizes, int n_in,
                              void* d_out, int out_size, void* d_ws, size_t ws_size,
                              hipStream_t stream) {
    const float* x   = (const float*)d_in[0];
    const int*   src = (const int*)d_in[1];
    const int*   dst = (const int*)d_in[2];
    float* out = (float*)d_out;
    float* S   = (float*)d_ws;   // n_nodes floats of scratch (400 KB)

    const int n_nodes = in_sizes[0] / IN_DIM;   // 100000
    const int n_edges = in_sizes[1];            // T*E = 1.5M

    // Phase 1: rowsums. 4 waves (rows) per 256-thread block.
    const int rows_per_block = 4;
    const int grid1 = (n_nodes + rows_per_block - 1) / rows_per_block;
    rowsum_kernel<<<grid1, 256, 0, stream>>>(x, S, n_nodes);

    // Phase 2: edge scores.
    const int grid2 = (n_edges + 255) / 256;
    edge_kernel<<<grid2, 256, 0, stream>>>(src, dst, S, out, n_edges);
}

// Round 3
// 107.596 us; speedup vs baseline: 1.0258x; 1.0258x over previous
//
#include <hip/hip_runtime.h>

// DotPred: score[t,e] = sum_d (x[src[t,e],d] - x[dst[t,e],d]) / sqrt(D)
//        = (rowsum(x)[src] - rowsum(x)[dst]) * (1/sqrt(D))
// Two-phase: (1) per-node rowsum into d_ws, (2) per-edge gather/subtract.
// Indices arrive as int32 (JAX x64 disabled; harness: integer -> const int*).

#define IN_DIM 128
#define INV_SQRT_D 0.08838834764831843f  // 1/sqrt(128)

// 32 lanes per row (float4 each = 128 floats), 2 rows per wave, 8 rows per 256-block.
__global__ void rowsum_kernel(const float4* __restrict__ x4,
                              float* __restrict__ S, int n_nodes) {
    const int wave = (blockIdx.x * blockDim.x + threadIdx.x) >> 6;
    const int lane = threadIdx.x & 63;
    const int row  = wave * 2 + (lane >> 5);
    if (row >= n_nodes) return;
    const int col = lane & 31;

    const float4 v = x4[(size_t)row * (IN_DIM / 4) + col];
    float s = (v.x + v.y) + (v.z + v.w);

    // Butterfly within each 32-lane half (xor of bits 0..4 stays in-half).
    #pragma unroll
    for (int off = 16; off > 0; off >>= 1)
        s += __shfl_xor(s, off, 64);

    if (col == 0) S[row] = s;   // lanes 0 and 32 write their rows
}

// 4 edges per thread: int4 index loads, float4 store.
__global__ void edge_kernel4(const int4* __restrict__ src4,
                             const int4* __restrict__ dst4,
                             const float* __restrict__ S,
                             float4* __restrict__ out4, int n4) {
    const int i = blockIdx.x * blockDim.x + threadIdx.x;
    if (i >= n4) return;
    const int4 s = src4[i];
    const int4 d = dst4[i];
    float4 o;
    o.x = (S[s.x] - S[d.x]) * INV_SQRT_D;
    o.y = (S[s.y] - S[d.y]) * INV_SQRT_D;
    o.z = (S[s.z] - S[d.z]) * INV_SQRT_D;
    o.w = (S[s.w] - S[d.w]) * INV_SQRT_D;
    out4[i] = o;
}

// Scalar tail (n % 4 != 0) — never triggers for n=1.5M but kept for robustness.
__global__ void edge_kernel_tail(const int* __restrict__ src,
                                 const int* __restrict__ dst,
                                 const float* __restrict__ S,
                                 float* __restrict__ out, int start, int n) {
    const int i = start + blockIdx.x * blockDim.x + threadIdx.x;
    if (i >= n) return;
    out[i] = (S[src[i]] - S[dst[i]]) * INV_SQRT_D;
}

extern "C" void kernel_launch(void* const* d_in, const int* in_sizes, int n_in,
                              void* d_out, int out_size, void* d_ws, size_t ws_size,
                              hipStream_t stream) {
    const float* x   = (const float*)d_in[0];
    const int*   src = (const int*)d_in[1];
    const int*   dst = (const int*)d_in[2];
    float* out = (float*)d_out;
    float* S   = (float*)d_ws;   // n_nodes floats of scratch (400 KB)

    const int n_nodes = in_sizes[0] / IN_DIM;   // 100000
    const int n_edges = in_sizes[1];            // T*E = 1.5M

    // Phase 1: rowsums. 8 rows per 256-thread block.
    const int grid1 = (n_nodes + 7) / 8;
    rowsum_kernel<<<grid1, 256, 0, stream>>>((const float4*)x, S, n_nodes);

    // Phase 2: edge scores, 4 per thread.
    const int n4 = n_edges >> 2;
    if (n4 > 0) {
        const int grid2 = (n4 + 255) / 256;
        edge_kernel4<<<grid2, 256, 0, stream>>>((const int4*)src, (const int4*)dst,
                                                S, (float4*)out, n4);
    }
    const int tail_start = n4 << 2;
    const int tail = n_edges - tail_start;
    if (tail > 0) {
        edge_kernel_tail<<<1, 256, 0, stream>>>(src, dst, S, out, tail_start, n_edges);
    }
}